// Round 6
// baseline (449.133 us; speedup 1.0000x reference)
//
#include <hip/hip_runtime.h>

// WarpAdjoint: bilinear forward-splat (scatter-add), summed over T.
// x_re, x_im: [B, T, M, N] f32;  u: [B, T, M, N, 2] f32 (u[...,0]=dx cols, u[...,1]=dy rows)
// Reference returns complex64 [B, M, N]; harness coerces to float32 (real part)
// unless out_size says otherwise -> runtime dispatch on out_size.
//
// Strategy: flows are ~N(0,1) so splat targets are local. Privatize into an LDS
// tile (32x32 + 8-halo) per block, accumulate with LDS f32 atomics, flush once
// with global atomics. Rare out-of-halo targets take a direct global atomic.

#define BB   8
#define TT   12
#define MM   384
#define NN   384
#define TS   32                 // tile size (image pixels)
#define HALO 8                  // covers ~8 sigma of N(0,1) flow
#define LW   (TS + 2*HALO)      // 48
#define TCH  6                  // t-slices per block
#define NTX  (NN/TS)            // 12
#define NTY  (MM/TS)            // 12
#define TILES (NTX*NTY)         // 144

template<bool CPLX>
__global__ __launch_bounds__(256)
void splat_kernel(const float* __restrict__ xr, const float* __restrict__ xi,
                  const float* __restrict__ u, float* __restrict__ out)
{
    // complex: interleaved (re,im), row stride 98 words (98%32==2 -> ~2-way, free)
    // real:    row stride 49 words (odd -> conflict-free columns)
    constexpr int ROWW = CPLX ? (2 * LW + 2) : (LW + 1);
    __shared__ float tile[LW * ROWW];
    for (int i = threadIdx.x; i < LW * ROWW; i += 256) tile[i] = 0.0f;
    __syncthreads();

    const int blk   = blockIdx.x;
    const int tilei = blk % TILES;
    const int tx    = tilei % NTX;
    const int ty    = tilei / NTX;
    const int bt    = blk / TILES;       // 0 .. BB*(TT/TCH)-1
    const int tc    = bt & 1;            // t-chunk (TT/TCH == 2)
    const int b     = bt >> 1;
    const int n0    = tx * TS;
    const int m0    = ty * TS;

    // 256 threads -> 32 rows x 8 col-groups of 4 consecutive pixels (float4 loads)
    const int lrow = threadIdx.x >> 3;        // 0..31
    const int lc4  = (threadIdx.x & 7) << 2;  // 0,4,...,28
    const int gm   = m0 + lrow;
    const int gn   = n0 + lc4;

    for (int tt = 0; tt < TCH; ++tt) {
        const int t = tc * TCH + tt;
        const size_t base = ((size_t)((b * TT + t) * MM + gm)) * NN + gn;
        const float4 vr = *reinterpret_cast<const float4*>(xr + base);
        float4 vi = make_float4(0.f, 0.f, 0.f, 0.f);
        if (CPLX) vi = *reinterpret_cast<const float4*>(xi + base);
        const float4 ua = *reinterpret_cast<const float4*>(u + 2 * base);
        const float4 ub = *reinterpret_cast<const float4*>(u + 2 * base + 4);
        const float re[4]  = {vr.x, vr.y, vr.z, vr.w};
        const float im[4]  = {vi.x, vi.y, vi.z, vi.w};
        const float dxs[4] = {ua.x, ua.z, ub.x, ub.z};   // u[...,0] of 4 pixels
        const float dys[4] = {ua.y, ua.w, ub.y, ub.w};   // u[...,1] of 4 pixels
        #pragma unroll
        for (int j = 0; j < 4; ++j) {
            const float fx = (float)(gn + j) + dxs[j];
            const float fy = (float)gm + dys[j];
            const float x0f = floorf(fx);
            const float y0f = floorf(fy);
            const int   x0  = (int)x0f;
            const int   y0  = (int)y0f;
            const float frx = fx - x0f;          // in [0,1)
            const float fry = fy - y0f;
            const float wx[2] = {1.0f - frx, frx};
            const float wy[2] = {1.0f - fry, fry};
            #pragma unroll
            for (int cy = 0; cy < 2; ++cy) {
                const int yc = y0 + cy;
                if ((unsigned)yc >= (unsigned)MM) continue;   // invalid row
                #pragma unroll
                for (int cx = 0; cx < 2; ++cx) {
                    const int xc = x0 + cx;
                    if ((unsigned)xc >= (unsigned)NN) continue; // invalid col
                    const float w  = wx[cx] * wy[cy];
                    const int  lr  = yc - (m0 - HALO);
                    const int  lc  = xc - (n0 - HALO);
                    if ((unsigned)lr < (unsigned)LW && (unsigned)lc < (unsigned)LW) {
                        if (CPLX) {
                            float* p = &tile[lr * ROWW + lc * 2];
                            atomicAdd(p,     w * re[j]);   // ds_add_f32
                            atomicAdd(p + 1, w * im[j]);
                        } else {
                            atomicAdd(&tile[lr * ROWW + lc], w * re[j]);
                        }
                    } else {
                        // out-of-halo (|u| > ~8 sigma): ~never, but must be correct
                        if (CPLX) {
                            float* q = out + (((size_t)b * MM + yc) * NN + xc) * 2;
                            unsafeAtomicAdd(q,     w * re[j]);
                            unsafeAtomicAdd(q + 1, w * im[j]);
                        } else {
                            unsafeAtomicAdd(out + ((size_t)b * MM + yc) * NN + xc,
                                            w * re[j]);
                        }
                    }
                }
            }
        }
    }
    __syncthreads();

    // Flush LDS tile (incl. halo) to global with atomics (halos overlap neighbors).
    for (int i = threadIdx.x; i < LW * LW; i += 256) {
        const int lr = i / LW;
        const int lc = i - lr * LW;
        const int gy = m0 - HALO + lr;
        const int gx = n0 - HALO + lc;
        if ((unsigned)gy < (unsigned)MM && (unsigned)gx < (unsigned)NN) {
            if (CPLX) {
                const float vre = tile[lr * ROWW + lc * 2];
                const float vim = tile[lr * ROWW + lc * 2 + 1];
                if (vre != 0.0f || vim != 0.0f) {
                    float* q = out + (((size_t)b * MM + gy) * NN + gx) * 2;
                    unsafeAtomicAdd(q,     vre);
                    unsafeAtomicAdd(q + 1, vim);
                }
            } else {
                const float v = tile[lr * ROWW + lc];
                if (v != 0.0f)
                    unsafeAtomicAdd(out + ((size_t)b * MM + gy) * NN + gx, v);
            }
        }
    }
}

extern "C" void kernel_launch(void* const* d_in, const int* in_sizes, int n_in,
                              void* d_out, int out_size, void* d_ws, size_t ws_size,
                              hipStream_t stream) {
    const float* xr = (const float*)d_in[0];
    const float* xi = (const float*)d_in[1];
    const float* u  = (const float*)d_in[2];
    float* out = (float*)d_out;

    // Zero exactly the harness-declared output extent (it poisons with 0xAA).
    hipMemsetAsync(d_out, 0, (size_t)out_size * sizeof(float), stream);

    const int grid = BB * (TT / TCH) * TILES;   // 8*2*144 = 2304 blocks
    const bool cplx = (out_size >= 2 * BB * MM * NN);
    if (cplx)
        splat_kernel<true ><<<grid, 256, 0, stream>>>(xr, xi, u, out);
    else
        splat_kernel<false><<<grid, 256, 0, stream>>>(xr, xi, u, out);
}